// Round 1
// baseline (2911.219 us; speedup 1.0000x reference)
//
#include <hip/hip_runtime.h>

#define SD 2048      // state dim
#define OD 512       // obs dim
#define NT 8192      // steps
#define BLK 64       // steps per block
#define KB 128       // number of blocks = NT/BLK
#define PROC_STD 0.31622776601683794f
#define OBS_STD  0.7071067811865476f

typedef __attribute__((ext_vector_type(8))) short v8s;
typedef __attribute__((ext_vector_type(4))) float v4f;

__device__ __forceinline__ unsigned short f2bf(float f) {
    union { float f; unsigned int u; } v; v.f = f;
    unsigned int r = v.u + 0x7fffu + ((v.u >> 16) & 1u);
    return (unsigned short)(r >> 16);
}

// ---------------- prep kernels ----------------

// Ebf = bf16(A - 0.99 I), M = c1 * (A - 0.99 I)
__global__ __launch_bounds__(256) void k_prep_A(const float* __restrict__ A,
                                                unsigned short* __restrict__ Ebf,
                                                float* __restrict__ M, float c1) {
    int idx = blockIdx.x * 256 + threadIdx.x;        // 0..SD*SD-1
    int r = idx >> 11, c = idx & 2047;
    float e = A[idx] - (r == c ? 0.99f : 0.0f);
    Ebf[idx] = f2bf(e);
    M[idx] = c1 * e;
}

__global__ __launch_bounds__(256) void k_prep_C(const float* __restrict__ C,
                                                unsigned short* __restrict__ Cbf) {
    int idx = blockIdx.x * 256 + threadIdx.x;        // 0..OD*SD-1
    Cbf[idx] = f2bf(C[idx]);
}

__global__ __launch_bounds__(256) void k_prep_S0(const float* __restrict__ s0,
                                                 float* __restrict__ Sb) {
    int idx = blockIdx.x * 256 + threadIdx.x;        // 0..SD-1
    Sb[idx] = s0[idx];                               // boundary state k=0
}

// U32[d][k] = PROC_STD * pn[(k*BLK+0)*SD + d]   (u^(1) init)
__global__ __launch_bounds__(256) void k_init_U(const float* __restrict__ pn,
                                                float* __restrict__ U32,
                                                unsigned short* __restrict__ Ubf) {
    int idx = blockIdx.x * 256 + threadIdx.x;        // 0..SD*KB-1
    int k = idx >> 11, d = idx & 2047;               // coalesced pn read over d
    float v = PROC_STD * pn[(size_t)(k * BLK) * SD + d];
    U32[d * KB + k] = v;
    Ubf[d * KB + k] = f2bf(v);
}

// S32[d][k] = Sb[k][d]  (pass-3 init from boundary states)
__global__ __launch_bounds__(256) void k_init_S(const float* __restrict__ Sb,
                                                float* __restrict__ S32,
                                                unsigned short* __restrict__ Sbf) {
    int idx = blockIdx.x * 256 + threadIdx.x;        // 0..SD*KB-1
    int d = idx >> 7, k = idx & 127;
    float v = Sb[k * SD + d];
    S32[idx] = v;
    Sbf[idx] = f2bf(v);
}

// ---------------- power GEMM: acc = L(2048x2048) @ X(2048x2048), M += coef*acc, Xout = bf16(acc)
__global__ __launch_bounds__(256) void k_gemm_pow(const unsigned short* __restrict__ L,
                                                  const unsigned short* __restrict__ X,
                                                  float* __restrict__ M,
                                                  unsigned short* __restrict__ Xout,
                                                  float coef) {
    __shared__ __align__(16) unsigned short Al[64 * 40];
    __shared__ __align__(16) unsigned short Xt[64 * 40];
    int tid = threadIdx.x, lane = tid & 63, w = tid >> 6;
    int m16 = lane & 15, q = lane >> 4;
    int bx = blockIdx.x;
    int tM = (bx & 31) * 64, tN = (bx >> 5) * 64;
    int ar = tid >> 2, ao = (tid & 3) * 8;           // A stage: 64 rows x 32 k
    int xk = tid >> 3, xn = (tid & 7) * 8;           // X stage: 32 k x 64 n
    int qb = xk >> 3;
    v4f acc[4] = {{0,0,0,0},{0,0,0,0},{0,0,0,0},{0,0,0,0}};

    v8s av = *(const v8s*)(L + (size_t)(tM + ar) * SD + ao);
    v8s xv = *(const v8s*)(X + (size_t)xk * SD + tN + xn);
    for (int k0 = 0; k0 < SD; k0 += 32) {
        *(v8s*)(Al + ar * 40 + ao) = av;
#pragma unroll
        for (int c = 0; c < 8; ++c) {
            int n = xn + c, sw = (n >> 3) & 3;       // XOR swizzle vs bank conflicts
            Xt[n * 40 + (((qb ^ sw) << 3) | (xk & 7))] = xv[c];
        }
        __syncthreads();
        if (k0 + 32 < SD) {                           // register prefetch
            av = *(const v8s*)(L + (size_t)(tM + ar) * SD + (k0 + 32) + ao);
            xv = *(const v8s*)(X + (size_t)(k0 + 32 + xk) * SD + tN + xn);
        }
        v8s a = *(const v8s*)(Al + (w * 16 + m16) * 40 + q * 8);
#pragma unroll
        for (int c = 0; c < 4; ++c) {
            int nl = c * 16 + m16, swn = (nl >> 3) & 3;
            v8s b = *(const v8s*)(Xt + nl * 40 + ((q ^ swn) << 3));
            acc[c] = __builtin_amdgcn_mfma_f32_16x16x32_bf16(a, b, acc[c], 0, 0, 0);
        }
        __syncthreads();
    }
#pragma unroll
    for (int c = 0; c < 4; ++c) {
#pragma unroll
        for (int j = 0; j < 4; ++j) {
            int r = tM + w * 16 + q * 4 + j;
            int col = tN + c * 16 + m16;
            size_t idx = (size_t)r * SD + col;
            float v = acc[c][j];
            M[idx] += coef * v;
            Xout[idx] = f2bf(v);
        }
    }
}

// ---------------- pass step GEMM (pass1 and pass3) ----------------
// blocks <256: state update out = 0.99*X32 + Ebf@Xbf + PROC_STD*pn[(k*BLK+i)]
// blocks >=256 (doC): obs: dout[t] = Cbf@Xbf + OBS_STD*on[t],  t = k*BLK+i
__global__ __launch_bounds__(256) void k_step(const unsigned short* __restrict__ Ebf,
                                              const unsigned short* __restrict__ Cbf,
                                              const unsigned short* __restrict__ Xbf,
                                              const float* __restrict__ X32,
                                              float* __restrict__ X32o,
                                              unsigned short* __restrict__ Xbfo,
                                              const float* __restrict__ pn,
                                              const float* __restrict__ on,
                                              float* __restrict__ dout,
                                              int i, int doA) {
    __shared__ __align__(16) unsigned short Al[32 * 72];
    __shared__ __align__(16) unsigned short Xt[32 * 72];
    int bx = blockIdx.x;
    int isC = (bx >= 256);
    if (!isC && !doA) return;
    const unsigned short* L = isC ? Cbf : Ebf;
    int bx2 = isC ? bx - 256 : bx;
    int tM, tN;
    if (isC) { tM = (bx2 & 15) * 32; tN = (bx2 >> 4) * 32; }
    else     { tM = (bx2 & 63) * 32; tN = (bx2 >> 6) * 32; }
    int tid = threadIdx.x, lane = tid & 63, w = tid >> 6;
    int m16 = lane & 15, q = lane >> 4;
    int ar = tid >> 3, ao = (tid & 7) * 8;           // A stage: 32 rows x 64 k
    int xk = tid >> 2, xn = (tid & 3) * 8;           // X stage: 64 k x 32 n
    int qb = xk >> 3;
    v4f acc = {0, 0, 0, 0};

    v8s av = *(const v8s*)(L + (size_t)(tM + ar) * SD + ao);
    v8s xv = *(const v8s*)(Xbf + (size_t)xk * KB + tN + xn);
    int nl = (w & 1) * 16 + m16;
    int swn = (nl >> 3) & 3;
    int rl = (w >> 1) * 16 + m16;
    for (int k0 = 0; k0 < SD; k0 += 64) {
        *(v8s*)(Al + ar * 72 + ao) = av;
#pragma unroll
        for (int c = 0; c < 8; ++c) {
            int n = xn + c, sw = (n >> 3) & 3;
            Xt[n * 72 + (((qb ^ sw) << 3) | (xk & 7))] = xv[c];
        }
        __syncthreads();
        if (k0 + 64 < SD) {
            av = *(const v8s*)(L + (size_t)(tM + ar) * SD + (k0 + 64) + ao);
            xv = *(const v8s*)(Xbf + (size_t)(k0 + 64 + xk) * KB + tN + xn);
        }
#pragma unroll
        for (int ch = 0; ch < 2; ++ch) {
            v8s a = *(const v8s*)(Al + rl * 72 + ch * 32 + q * 8);
            int q2 = ch * 4 + q;
            v8s b = *(const v8s*)(Xt + nl * 72 + ((q2 ^ swn) << 3));
            acc = __builtin_amdgcn_mfma_f32_16x16x32_bf16(a, b, acc, 0, 0, 0);
        }
        __syncthreads();
    }
    if (!isC) {
#pragma unroll
        for (int j = 0; j < 4; ++j) {
            int r = tM + (w >> 1) * 16 + q * 4 + j;
            int kc = tN + (w & 1) * 16 + m16;
            int idx = r * KB + kc;
            float v = 0.99f * X32[idx] + acc[j]
                    + PROC_STD * pn[(size_t)(kc * BLK + i) * SD + r];
            X32o[idx] = v;
            Xbfo[idx] = f2bf(v);
        }
    } else {
        float* obsT = (float*)Al;                    // 32x33 floats fits in Al
        int lo = (w >> 1) * 16 + q * 4;
        int lk = (w & 1) * 16 + m16;
#pragma unroll
        for (int j = 0; j < 4; ++j) obsT[(lo + j) * 33 + lk] = acc[j];
        __syncthreads();
        int lk2 = tid >> 3;                          // 0..31 (k within tile)
        int oo = (tid & 7) * 4;                      // 0..28 (o within tile)
        int t = (tN + lk2) * BLK + i;
        size_t base = (size_t)t * OD + tM + oo;
        float4 n4 = *(const float4*)(on + base);
        float4 o4;
        o4.x = obsT[(oo + 0) * 33 + lk2] + OBS_STD * n4.x;
        o4.y = obsT[(oo + 1) * 33 + lk2] + OBS_STD * n4.y;
        o4.z = obsT[(oo + 2) * 33 + lk2] + OBS_STD * n4.z;
        o4.w = obsT[(oo + 3) * 33 + lk2] + OBS_STD * n4.w;
        *(float4*)(dout + base) = o4;
    }
}

// ---------------- pass 2: boundary matvec  s' = a64*s + M@s + Ufin[:,k] ----------------
__global__ __launch_bounds__(256) void k_matvec(const float* __restrict__ M,
                                                const float* __restrict__ Sb_in,
                                                const float* __restrict__ Ufin,
                                                float* __restrict__ Sb_out,
                                                int k, float a64) {
    int lane = threadIdx.x & 63;
    int wg = blockIdx.x * 4 + (threadIdx.x >> 6);    // 0..1023
    const float4* S4 = (const float4*)Sb_in;
#pragma unroll
    for (int rep = 0; rep < 2; ++rep) {
        int r = wg + rep * 1024;
        const float4* Mr = (const float4*)(M + (size_t)r * SD);
        float acc = 0.f;
#pragma unroll
        for (int it = 0; it < 8; ++it) {
            float4 m4 = Mr[lane + it * 64];
            float4 s4 = S4[lane + it * 64];
            acc += m4.x * s4.x + m4.y * s4.y + m4.z * s4.z + m4.w * s4.w;
        }
#pragma unroll
        for (int off = 32; off; off >>= 1) acc += __shfl_down(acc, off);
        if (lane == 0) Sb_out[r] = a64 * Sb_in[r] + acc + Ufin[r * KB + k];
    }
}

// ---------------- host ----------------
extern "C" void kernel_launch(void* const* d_in, const int* in_sizes, int n_in,
                              void* d_out, int out_size, void* d_ws, size_t ws_size,
                              hipStream_t stream) {
    const float* s0 = (const float*)d_in[0];
    const float* A  = (const float*)d_in[1];
    const float* C  = (const float*)d_in[2];
    const float* pn = (const float*)d_in[3];
    const float* on = (const float*)d_in[4];
    float* out = (float*)d_out;

    char* p = (char*)d_ws;
    auto take = [&](size_t n) { char* r = p; p += (n + 255) & ~(size_t)255; return r; };
    unsigned short* Ebf = (unsigned short*)take((size_t)SD * SD * 2);
    unsigned short* Cbf = (unsigned short*)take((size_t)OD * SD * 2);
    unsigned short* Xp0 = (unsigned short*)take((size_t)SD * SD * 2);
    unsigned short* Xp1 = (unsigned short*)take((size_t)SD * SD * 2);
    float* M = (float*)take((size_t)SD * SD * 4);
    float* U32[2] = {(float*)take((size_t)SD * KB * 4), (float*)take((size_t)SD * KB * 4)};
    unsigned short* Ubf[2] = {(unsigned short*)take((size_t)SD * KB * 2),
                              (unsigned short*)take((size_t)SD * KB * 2)};
    float* Sb = (float*)take((size_t)KB * SD * 4);
    float* S32[2] = {(float*)take((size_t)SD * KB * 4), (float*)take((size_t)SD * KB * 4)};
    unsigned short* Sbf[2] = {(unsigned short*)take((size_t)SD * KB * 2),
                              (unsigned short*)take((size_t)SD * KB * 2)};

    // A^64 = 0.99^64 I + sum_{m=1..6} C(64,m) 0.99^(64-m) E^m   (tail ~2e-6)
    double pw[65]; pw[0] = 1.0;
    for (int m = 1; m <= 64; ++m) pw[m] = pw[m - 1] * 0.99;
    const double bin[7] = {1, 64, 2016, 41664, 635376, 7624512, 74974368};
    float cf[7];
    for (int m = 1; m <= 6; ++m) cf[m] = (float)(bin[m] * pw[64 - m]);
    float a64 = (float)pw[64];

    k_prep_A<<<SD * SD / 256, 256, 0, stream>>>(A, Ebf, M, cf[1]);
    k_prep_C<<<OD * SD / 256, 256, 0, stream>>>(C, Cbf);
    k_prep_S0<<<SD / 256, 256, 0, stream>>>(s0, Sb);

    // powers E^2..E^6 (bf16 MFMA), accumulate into M
    k_gemm_pow<<<1024, 256, 0, stream>>>(Ebf, Ebf, M, Xp0, cf[2]);
    k_gemm_pow<<<1024, 256, 0, stream>>>(Ebf, Xp0, M, Xp1, cf[3]);
    k_gemm_pow<<<1024, 256, 0, stream>>>(Ebf, Xp1, M, Xp0, cf[4]);
    k_gemm_pow<<<1024, 256, 0, stream>>>(Ebf, Xp0, M, Xp1, cf[5]);
    k_gemm_pow<<<1024, 256, 0, stream>>>(Ebf, Xp1, M, Xp0, cf[6]);

    // pass 1: noise-only block states, batched over 128 blocks
    k_init_U<<<SD * KB / 256, 256, 0, stream>>>(pn, U32[0], Ubf[0]);
    int cur = 0;
    for (int i = 1; i <= 63; ++i) {
        k_step<<<256, 256, 0, stream>>>(Ebf, Cbf, Ubf[cur], U32[cur],
                                        U32[cur ^ 1], Ubf[cur ^ 1],
                                        pn, on, out, i, 1);
        cur ^= 1;
    }   // cur == 1: U32[1] holds u^(64) per block

    // pass 2: sequential boundary stitch with A^64
    for (int k = 0; k < KB - 1; ++k)
        k_matvec<<<256, 256, 0, stream>>>(M, Sb + (size_t)k * SD, U32[cur],
                                          Sb + (size_t)(k + 1) * SD, k, a64);

    // pass 3: replay blocks from boundary states, fused obs output
    k_init_S<<<SD * KB / 256, 256, 0, stream>>>(Sb, S32[0], Sbf[0]);
    int cs = 0;
    for (int i = 0; i < 64; ++i) {
        k_step<<<320, 256, 0, stream>>>(Ebf, Cbf, Sbf[cs], S32[cs],
                                        S32[cs ^ 1], Sbf[cs ^ 1],
                                        pn, on, out, i, (i < 63) ? 1 : 0);
        cs ^= 1;
    }
}